// Round 7
// baseline (885.836 us; speedup 1.0000x reference)
//
#include <hip/hip_runtime.h>

#define TT 512
#define NB 128   // batch
#define DD 128
#define HH 64
#define CC 45

__device__ __forceinline__ float sigf(float x) { return 1.0f / (1.0f + __expf(-x)); }

// LDS-only barrier: syncs LDS visibility WITHOUT draining vmcnt (global
// loads/stores stay in flight across steps). __syncthreads() would emit
// s_waitcnt vmcnt(0) before s_barrier — ~500-900 cyc of HBM/L3 latency
// serialized into every step (proven R5->R6: removing it cut 75us/dispatch).
#define LDS_BAR() asm volatile("s_waitcnt lgkmcnt(0)\n\ts_barrier" ::: "memory")

// ---------------------------------------------------------------------------
// GEMM: Cout[m][0:512] = A[m][0:128] @ [Wf | Wb] + [biasf | biasb]
// A: [65536][128] row-major. Wf/Wb: [128][256] row-major. Cout: [65536][512].
// BM=128, BN=128, BK=32, 256 threads, 8x8 accumulation per thread. f32 VALU.
// ---------------------------------------------------------------------------
__global__ __launch_bounds__(256) void gemm_xz(
    const float* __restrict__ A, const float* __restrict__ Wf,
    const float* __restrict__ Wb, const float* __restrict__ biasf,
    const float* __restrict__ biasb, float* __restrict__ Cout)
{
    __shared__ float As[32][132];   // [k][m], padded
    __shared__ float Bs[32][132];   // [k][n], padded
    const int tid = threadIdx.x;
    const int m0 = blockIdx.x * 128;
    const int n0 = blockIdx.y * 128;          // global col in [0,512)
    const float* W   = (n0 < 256) ? Wf : Wb;
    const float* bia = (n0 < 256) ? biasf : biasb;
    const int nc0 = n0 & 255;

    const int ty = tid >> 4, tx = tid & 15;
    const int arow = tid >> 3, akv = (tid & 7) << 2;
    const int bkr  = tid >> 5, bnv = (tid & 31) << 2;

    float acc[8][8];
    #pragma unroll
    for (int i = 0; i < 8; ++i)
        #pragma unroll
        for (int j = 0; j < 8; ++j) acc[i][j] = 0.f;

    for (int k0 = 0; k0 < 128; k0 += 32) {
        #pragma unroll
        for (int rr = 0; rr < 4; ++rr) {
            const int r = arow + rr * 32;
            const float4 av = *(const float4*)&A[(size_t)(m0 + r) * 128 + k0 + akv];
            As[akv + 0][r] = av.x; As[akv + 1][r] = av.y;
            As[akv + 2][r] = av.z; As[akv + 3][r] = av.w;
        }
        #pragma unroll
        for (int rr = 0; rr < 4; ++rr) {
            const int kr = bkr + rr * 8;
            *(float4*)&Bs[kr][bnv] =
                *(const float4*)&W[(size_t)(k0 + kr) * 256 + nc0 + bnv];
        }
        __syncthreads();
        #pragma unroll
        for (int k = 0; k < 32; ++k) {
            float av[8], bv[8];
            *(float4*)&av[0] = *(const float4*)&As[k][ty * 8];
            *(float4*)&av[4] = *(const float4*)&As[k][ty * 8 + 4];
            *(float4*)&bv[0] = *(const float4*)&Bs[k][tx * 8];
            *(float4*)&bv[4] = *(const float4*)&Bs[k][tx * 8 + 4];
            #pragma unroll
            for (int i = 0; i < 8; ++i)
                #pragma unroll
                for (int j = 0; j < 8; ++j)
                    acc[i][j] = __fmaf_rn(av[i], bv[j], acc[i][j]);
        }
        __syncthreads();
    }
    #pragma unroll
    for (int i = 0; i < 8; ++i) {
        const size_t rbase = (size_t)(m0 + ty * 8 + i) * 512 + n0 + tx * 8;
        float4 o;
        o.x = acc[i][0] + bia[nc0 + tx * 8 + 0];
        o.y = acc[i][1] + bia[nc0 + tx * 8 + 1];
        o.z = acc[i][2] + bia[nc0 + tx * 8 + 2];
        o.w = acc[i][3] + bia[nc0 + tx * 8 + 3];
        *(float4*)&Cout[rbase] = o;
        o.x = acc[i][4] + bia[nc0 + tx * 8 + 4];
        o.y = acc[i][5] + bia[nc0 + tx * 8 + 5];
        o.z = acc[i][6] + bia[nc0 + tx * 8 + 6];
        o.w = acc[i][7] + bia[nc0 + tx * 8 + 7];
        *(float4*)&Cout[rbase + 4] = o;
    }
}

// ---------------------------------------------------------------------------
// LSTM recurrence: column-split + asm-pinned U + LDS-only barrier (1/step)
// + depth-2 xz prefetch. 256 blocks (batch x dir) x 256 threads.
// Wave w owns columns [w*16, w*16+16); lane = gate*16 + colL.
// Each lane: 64 FMA (pinned U VGPRs x broadcast LDS h) -> z[gate][col];
// gate activations in parallel; i/f/g/o combined intra-wave (3 shfl_xor);
// c replicated in the 4 gate lanes of a column. ONE LDS_BAR per step.
// Global xz loads issued 2 steps ahead; hout stores fire-and-forget —
// neither is ever drained by a barrier.
// ---------------------------------------------------------------------------
__global__ __launch_bounds__(256, 1) void lstm_rec_csb(
    const float* __restrict__ xz, const float* __restrict__ Uf,
    const float* __restrict__ Ubw, float* __restrict__ hout)
{
    const int b   = blockIdx.x & 127;
    const int dir = blockIdx.x >> 7;
    const int tid = threadIdx.x;
    const int w    = tid >> 6;          // wave 0..3
    const int lane = tid & 63;
    const int gate = lane >> 4;         // 0:i 1:f 2:g 3:o
    const int colL = lane & 15;
    const int col  = w * 16 + colL;     // h column 0..63
    const int gcol = gate * 64 + col;
    const float* U = dir ? Ubw : Uf;

    __shared__ float hbuf[2][64];

    // 64 U values for this lane's (gate,col), pinned into registers.
    // (R3/R4 lesson: unpinned invariant loads get rematerialized into the
    // loop -> 8.6GB/dispatch L2 traffic. R5/R6 proved the asm pin holds.)
    const float* Ug = U + gcol;
#define DU(a,b2,c2,d2) \
    float u##a = Ug[(a)*256]; float u##b2 = Ug[(b2)*256]; \
    float u##c2 = Ug[(c2)*256]; float u##d2 = Ug[(d2)*256];
    DU(0,1,2,3)     DU(4,5,6,7)     DU(8,9,10,11)   DU(12,13,14,15)
    DU(16,17,18,19) DU(20,21,22,23) DU(24,25,26,27) DU(28,29,30,31)
    DU(32,33,34,35) DU(36,37,38,39) DU(40,41,42,43) DU(44,45,46,47)
    DU(48,49,50,51) DU(52,53,54,55) DU(56,57,58,59) DU(60,61,62,63)
#undef DU
    asm volatile("" : "+v"(u0),"+v"(u1),"+v"(u2),"+v"(u3),"+v"(u4),"+v"(u5),
        "+v"(u6),"+v"(u7),"+v"(u8),"+v"(u9),"+v"(u10),"+v"(u11),"+v"(u12),
        "+v"(u13),"+v"(u14),"+v"(u15));
    asm volatile("" : "+v"(u16),"+v"(u17),"+v"(u18),"+v"(u19),"+v"(u20),
        "+v"(u21),"+v"(u22),"+v"(u23),"+v"(u24),"+v"(u25),"+v"(u26),"+v"(u27),
        "+v"(u28),"+v"(u29),"+v"(u30),"+v"(u31));
    asm volatile("" : "+v"(u32),"+v"(u33),"+v"(u34),"+v"(u35),"+v"(u36),
        "+v"(u37),"+v"(u38),"+v"(u39),"+v"(u40),"+v"(u41),"+v"(u42),"+v"(u43),
        "+v"(u44),"+v"(u45),"+v"(u46),"+v"(u47));
    asm volatile("" : "+v"(u48),"+v"(u49),"+v"(u50),"+v"(u51),"+v"(u52),
        "+v"(u53),"+v"(u54),"+v"(u55),"+v"(u56),"+v"(u57),"+v"(u58),"+v"(u59),
        "+v"(u60),"+v"(u61),"+v"(u62),"+v"(u63));

    if (tid < 64) hbuf[0][tid] = 0.f;
    float c = 0.f;
    __syncthreads();

    const float* xzb = xz + (size_t)b * TT * 512 + (size_t)dir * 256 + gcol;
    float*       hob = hout + (size_t)b * TT * 128 + (size_t)dir * 64 + col;

    int trow = dir ? (TT - 1) : 0;
    const int ts = dir ? -1 : 1;
    float xc = xzb[(size_t)trow * 512];               // step s
    float x1 = xzb[(size_t)(trow + ts) * 512];        // step s+1

    for (int s = 0; s < TT; ++s) {
        const int p = s & 1;
        float x2 = 0.f;
        if (s + 2 < TT) x2 = xzb[(size_t)(trow + 2 * ts) * 512];  // depth-2

        // z = x + U[:,gcol] . h  (broadcast float4 LDS reads, 4 partials)
        float a0 = 0.f, a1 = 0.f, a2 = 0.f, a3 = 0.f;
#define ACC(J, A,B,C,D) { const float4 hv = *(const float4*)&hbuf[p][4*(J)]; \
        a0 = __fmaf_rn(hv.x, A, a0); a1 = __fmaf_rn(hv.y, B, a1); \
        a2 = __fmaf_rn(hv.z, C, a2); a3 = __fmaf_rn(hv.w, D, a3); }
        ACC(0 ,u0 ,u1 ,u2 ,u3 ) ACC(1 ,u4 ,u5 ,u6 ,u7 )
        ACC(2 ,u8 ,u9 ,u10,u11) ACC(3 ,u12,u13,u14,u15)
        ACC(4 ,u16,u17,u18,u19) ACC(5 ,u20,u21,u22,u23)
        ACC(6 ,u24,u25,u26,u27) ACC(7 ,u28,u29,u30,u31)
        ACC(8 ,u32,u33,u34,u35) ACC(9 ,u36,u37,u38,u39)
        ACC(10,u40,u41,u42,u43) ACC(11,u44,u45,u46,u47)
        ACC(12,u48,u49,u50,u51) ACC(13,u52,u53,u54,u55)
        ACC(14,u56,u57,u58,u59) ACC(15,u60,u61,u62,u63)
#undef ACC
        const float z = xc + ((a0 + a1) + (a2 + a3));

        // own gate's activation (relu for gate 2, sigmoid otherwise)
        const float a = (gate == 2) ? fmaxf(z, 0.f) : sigf(z);

        // intra-wave all-gather of the 4 gate activations for this column
        const float b0 = __shfl_xor(a, 16);
        const float b1 = __shfl_xor(a, 32);
        const float b2 = __shfl_xor(b0, 32);
        const float ai = (gate == 0) ? a : (gate == 1) ? b0 : (gate == 2) ? b1 : b2;
        const float af = (gate == 1) ? a : (gate == 0) ? b0 : (gate == 3) ? b1 : b2;
        const float ag = (gate == 2) ? a : (gate == 3) ? b0 : (gate == 0) ? b1 : b2;
        const float ao = (gate == 3) ? a : (gate == 2) ? b0 : (gate == 1) ? b1 : b2;

        // replicated state update (all 4 gate lanes of a column agree)
        c = af * c + ai * ag;            // ag already relu'd
        const float h = ao * fmaxf(c, 0.f);

        if (gate == 0) {                 // one writer per column
            hbuf[p ^ 1][col] = h;
            hob[(size_t)trow * 128] = h; // fire-and-forget, never drained
        }

        LDS_BAR();                       // ONE barrier/step; WAR safe (parity)

        xc = x1; x1 = x2;
        trow += ts;
    }
}

// ---------------------------------------------------------------------------
// Dense + softmax: out[m][c] = softmax_c( h2[m][:] @ Wd[:,c] + bd[c] )
// ---------------------------------------------------------------------------
__global__ __launch_bounds__(256) void dense_softmax(
    const float* __restrict__ h2, const float* __restrict__ Wd,
    const float* __restrict__ bd, float* __restrict__ out)
{
    __shared__ float Wl[128 * 45];
    __shared__ float bl[48];
    __shared__ float hrow[4][128];
    const int tid = threadIdx.x;
    for (int i = tid; i < 128 * 45; i += 256) Wl[i] = Wd[i];
    if (tid < 45) bl[tid] = bd[tid];
    __syncthreads();

    const int w = tid >> 6, l = tid & 63;
    const size_t row0 = (size_t)blockIdx.x * 64;
    for (int rr = 0; rr < 16; ++rr) {
        const size_t m = row0 + (size_t)rr * 4 + w;
        const float2 hv = *(const float2*)&h2[m * 128 + l * 2];
        hrow[w][l * 2] = hv.x;
        hrow[w][l * 2 + 1] = hv.y;
        __syncthreads();
        float lg = -3.0e38f;
        if (l < CC) {
            lg = bl[l];
            #pragma unroll 8
            for (int k = 0; k < 128; ++k) lg = __fmaf_rn(hrow[w][k], Wl[k * 45 + l], lg);
        }
        float mx = lg;
        #pragma unroll
        for (int off = 32; off >= 1; off >>= 1) mx = fmaxf(mx, __shfl_xor(mx, off));
        const float e = (l < CC) ? __expf(lg - mx) : 0.f;
        float sm = e;
        #pragma unroll
        for (int off = 32; off >= 1; off >>= 1) sm += __shfl_xor(sm, off);
        if (l < CC) out[m * 45 + l] = e / sm;
        __syncthreads();
    }
}

// ---------------------------------------------------------------------------
extern "C" void kernel_launch(void* const* d_in, const int* in_sizes, int n_in,
                              void* d_out, int out_size, void* d_ws, size_t ws_size,
                              hipStream_t stream)
{
    const float* x   = (const float*)d_in[0];
    const float* W1f = (const float*)d_in[1];
    const float* U1f = (const float*)d_in[2];
    const float* b1f = (const float*)d_in[3];
    const float* W1b = (const float*)d_in[4];
    const float* U1b = (const float*)d_in[5];
    const float* b1b = (const float*)d_in[6];
    const float* W2f = (const float*)d_in[7];
    const float* U2f = (const float*)d_in[8];
    const float* b2f = (const float*)d_in[9];
    const float* W2b = (const float*)d_in[10];
    const float* U2b = (const float*)d_in[11];
    const float* b2b = (const float*)d_in[12];
    const float* Wd  = (const float*)d_in[13];
    const float* bd  = (const float*)d_in[14];

    // Workspace layout (160 MiB):
    //   xz : 65536 x 512 f32 = 128 MiB   (reused by layer 1 and layer 2)
    //   h  : 65536 x 128 f32 =  32 MiB   (h1, then overwritten by h2)
    float* xz = (float*)d_ws;
    float* h  = (float*)((char*)d_ws + (size_t)65536 * 512 * 4);

    const dim3 gemm_grid(512, 4);      // 65536/128 m-tiles, 512/128 n-tiles
    const dim3 rec_grid(256);          // 128 batch x 2 directions
    const dim3 dense_grid(1024);       // 65536/64 rows

    // Layer 1
    gemm_xz<<<gemm_grid, dim3(256), 0, stream>>>(x, W1f, W1b, b1f, b1b, xz);
    lstm_rec_csb<<<rec_grid, dim3(256), 0, stream>>>(xz, U1f, U1b, h);
    // Layer 2
    gemm_xz<<<gemm_grid, dim3(256), 0, stream>>>(h, W2f, W2b, b2f, b2b, xz);
    lstm_rec_csb<<<rec_grid, dim3(256), 0, stream>>>(xz, U2f, U2b, h);
    // Head
    dense_softmax<<<dense_grid, dim3(256), 0, stream>>>(h, Wd, bd, (float*)d_out);
}

// Round 8
// 862.377 us; speedup vs baseline: 1.0272x; 1.0272x over previous
//
#include <hip/hip_runtime.h>

#define TT 512
#define NB 128   // batch
#define DD 128
#define HH 64
#define CC 45

__device__ __forceinline__ float sigf(float x) { return 1.0f / (1.0f + __expf(-x)); }

// LDS-only barrier: syncs LDS visibility WITHOUT draining vmcnt (global
// loads/stores stay in flight across steps). __syncthreads() would emit
// s_waitcnt vmcnt(0) before s_barrier — proven worth 75us/dispatch (R5->R6).
#define LDS_BAR() asm volatile("s_waitcnt lgkmcnt(0)\n\ts_barrier" ::: "memory")

// ---------------------------------------------------------------------------
// GEMM: Cout[m][0:512] = A[m][0:128] @ [Wf | Wb] + [biasf | biasb]
// A: [65536][128] row-major. Wf/Wb: [128][256] row-major. Cout: [65536][512].
// BM=128, BN=128, BK=32, 256 threads, 8x8 accumulation per thread. f32 VALU.
// ---------------------------------------------------------------------------
__global__ __launch_bounds__(256) void gemm_xz(
    const float* __restrict__ A, const float* __restrict__ Wf,
    const float* __restrict__ Wb, const float* __restrict__ biasf,
    const float* __restrict__ biasb, float* __restrict__ Cout)
{
    __shared__ float As[32][132];   // [k][m], padded
    __shared__ float Bs[32][132];   // [k][n], padded
    const int tid = threadIdx.x;
    const int m0 = blockIdx.x * 128;
    const int n0 = blockIdx.y * 128;          // global col in [0,512)
    const float* W   = (n0 < 256) ? Wf : Wb;
    const float* bia = (n0 < 256) ? biasf : biasb;
    const int nc0 = n0 & 255;

    const int ty = tid >> 4, tx = tid & 15;
    const int arow = tid >> 3, akv = (tid & 7) << 2;
    const int bkr  = tid >> 5, bnv = (tid & 31) << 2;

    float acc[8][8];
    #pragma unroll
    for (int i = 0; i < 8; ++i)
        #pragma unroll
        for (int j = 0; j < 8; ++j) acc[i][j] = 0.f;

    for (int k0 = 0; k0 < 128; k0 += 32) {
        #pragma unroll
        for (int rr = 0; rr < 4; ++rr) {
            const int r = arow + rr * 32;
            const float4 av = *(const float4*)&A[(size_t)(m0 + r) * 128 + k0 + akv];
            As[akv + 0][r] = av.x; As[akv + 1][r] = av.y;
            As[akv + 2][r] = av.z; As[akv + 3][r] = av.w;
        }
        #pragma unroll
        for (int rr = 0; rr < 4; ++rr) {
            const int kr = bkr + rr * 8;
            *(float4*)&Bs[kr][bnv] =
                *(const float4*)&W[(size_t)(k0 + kr) * 256 + nc0 + bnv];
        }
        __syncthreads();
        #pragma unroll
        for (int k = 0; k < 32; ++k) {
            float av[8], bv[8];
            *(float4*)&av[0] = *(const float4*)&As[k][ty * 8];
            *(float4*)&av[4] = *(const float4*)&As[k][ty * 8 + 4];
            *(float4*)&bv[0] = *(const float4*)&Bs[k][tx * 8];
            *(float4*)&bv[4] = *(const float4*)&Bs[k][tx * 8 + 4];
            #pragma unroll
            for (int i = 0; i < 8; ++i)
                #pragma unroll
                for (int j = 0; j < 8; ++j)
                    acc[i][j] = __fmaf_rn(av[i], bv[j], acc[i][j]);
        }
        __syncthreads();
    }
    #pragma unroll
    for (int i = 0; i < 8; ++i) {
        const size_t rbase = (size_t)(m0 + ty * 8 + i) * 512 + n0 + tx * 8;
        float4 o;
        o.x = acc[i][0] + bia[nc0 + tx * 8 + 0];
        o.y = acc[i][1] + bia[nc0 + tx * 8 + 1];
        o.z = acc[i][2] + bia[nc0 + tx * 8 + 2];
        o.w = acc[i][3] + bia[nc0 + tx * 8 + 3];
        *(float4*)&Cout[rbase] = o;
        o.x = acc[i][4] + bia[nc0 + tx * 8 + 4];
        o.y = acc[i][5] + bia[nc0 + tx * 8 + 5];
        o.z = acc[i][6] + bia[nc0 + tx * 8 + 6];
        o.w = acc[i][7] + bia[nc0 + tx * 8 + 7];
        *(float4*)&Cout[rbase + 4] = o;
    }
}

// ---------------------------------------------------------------------------
// LSTM recurrence, 16-wave shuffle-reduce. 256 blocks (batch x dir) x 1024.
// Lane bits: [5:4]=gate, [3:2]=kq, [1:0]=colL. Wave w owns cols w*4..w*4+3.
// Per lane: 16 pinned U VGPRs (<=16/lane stays resident: R5 VGPR=24; 64/lane
// always spills: R3/R4/R7). Step: 16 FMA partial -> kq-reduce via shfl_xor
// (4,8) -> own-gate activation -> gate gather via shfl_xor(16,32) -> c/h
// update replicated -> writer lane (lane<4) stores h to LDS + global.
// ONE LDS_BAR per step; xz prefetched 2 steps ahead; stores fire-and-forget.
// ---------------------------------------------------------------------------
__global__ __launch_bounds__(1024, 1) void lstm_rec_w16(
    const float* __restrict__ xz, const float* __restrict__ Uf,
    const float* __restrict__ Ubw, float* __restrict__ hout)
{
    const int b   = blockIdx.x & 127;
    const int dir = blockIdx.x >> 7;
    const int tid = threadIdx.x;
    const int w    = tid >> 6;          // wave 0..15
    const int lane = tid & 63;
    const int colL = lane & 3;
    const int kq   = (lane >> 2) & 3;   // K-quarter
    const int gate = lane >> 4;         // 0:i 1:f 2:g 3:o
    const int col  = w * 4 + colL;      // h column 0..63
    const int gcol = gate * 64 + col;
    const float* U = dir ? Ubw : Uf;

    __shared__ float hbuf[2][64];

    // 16 U values: U[kq*16 + j][gcol], pinned (asm => not rematerializable;
    // small enough that the RA keeps them resident instead of spilling).
    const float* Ug = U + (size_t)(kq * 16) * 256 + gcol;
    float u0  = Ug[0 * 256],  u1  = Ug[1 * 256],  u2  = Ug[2 * 256],  u3  = Ug[3 * 256];
    float u4  = Ug[4 * 256],  u5  = Ug[5 * 256],  u6  = Ug[6 * 256],  u7  = Ug[7 * 256];
    float u8  = Ug[8 * 256],  u9  = Ug[9 * 256],  u10 = Ug[10 * 256], u11 = Ug[11 * 256];
    float u12 = Ug[12 * 256], u13 = Ug[13 * 256], u14 = Ug[14 * 256], u15 = Ug[15 * 256];
    asm volatile("" : "+v"(u0), "+v"(u1), "+v"(u2), "+v"(u3),
                      "+v"(u4), "+v"(u5), "+v"(u6), "+v"(u7),
                      "+v"(u8), "+v"(u9), "+v"(u10), "+v"(u11),
                      "+v"(u12), "+v"(u13), "+v"(u14), "+v"(u15));

    if (tid < 64) hbuf[0][tid] = 0.f;
    float c = 0.f;
    __syncthreads();

    const float* xzb = xz + (size_t)b * TT * 512 + (size_t)dir * 256 + gcol;
    float*       hob = hout + (size_t)b * TT * 128 + (size_t)dir * 64 + col;

    int trow = dir ? (TT - 1) : 0;
    const int ts = dir ? -1 : 1;
    float xc = xzb[(size_t)trow * 512];            // step s
    float x1 = xzb[(size_t)(trow + ts) * 512];     // step s+1

    for (int s = 0; s < TT; ++s) {
        const int p = s & 1;
        float x2 = 0.f;
        if (s + 2 < TT) x2 = xzb[(size_t)(trow + 2 * ts) * 512];  // depth-2

        // 16-FMA partial over this lane's K-quarter (broadcast LDS reads)
        const float4 h0 = *(const float4*)&hbuf[p][kq * 16 + 0];
        const float4 h1 = *(const float4*)&hbuf[p][kq * 16 + 4];
        const float4 h2 = *(const float4*)&hbuf[p][kq * 16 + 8];
        const float4 h3 = *(const float4*)&hbuf[p][kq * 16 + 12];
        float a0 = 0.f, a1 = 0.f, a2 = 0.f, a3 = 0.f;
        a0 = __fmaf_rn(h0.x, u0,  a0); a1 = __fmaf_rn(h0.y, u1,  a1);
        a2 = __fmaf_rn(h0.z, u2,  a2); a3 = __fmaf_rn(h0.w, u3,  a3);
        a0 = __fmaf_rn(h1.x, u4,  a0); a1 = __fmaf_rn(h1.y, u5,  a1);
        a2 = __fmaf_rn(h1.z, u6,  a2); a3 = __fmaf_rn(h1.w, u7,  a3);
        a0 = __fmaf_rn(h2.x, u8,  a0); a1 = __fmaf_rn(h2.y, u9,  a1);
        a2 = __fmaf_rn(h2.z, u10, a2); a3 = __fmaf_rn(h2.w, u11, a3);
        a0 = __fmaf_rn(h3.x, u12, a0); a1 = __fmaf_rn(h3.y, u13, a1);
        a2 = __fmaf_rn(h3.z, u14, a2); a3 = __fmaf_rn(h3.w, u15, a3);
        float part = (a0 + a1) + (a2 + a3);

        // kq-reduce within the wave (lane bits [3:2])
        part += __shfl_xor(part, 4);
        part += __shfl_xor(part, 8);
        const float z = xc + part;

        // own gate's activation (relu for gate 2, sigmoid otherwise)
        const float a = (gate == 2) ? fmaxf(z, 0.f) : sigf(z);

        // gate all-gather (lane bits [5:4]): a=g, b0=g^1, b1=g^2, b2=g^3
        const float b0 = __shfl_xor(a, 16);
        const float b1 = __shfl_xor(a, 32);
        const float b2 = __shfl_xor(b0, 32);
        const float ai = (gate == 0) ? a : (gate == 1) ? b0 : (gate == 2) ? b1 : b2;
        const float af = (gate == 1) ? a : (gate == 0) ? b0 : (gate == 3) ? b1 : b2;
        const float ag = (gate == 2) ? a : (gate == 3) ? b0 : (gate == 0) ? b1 : b2;
        const float ao = (gate == 3) ? a : (gate == 2) ? b0 : (gate == 1) ? b1 : b2;

        // replicated state update (all 16 lanes of a column agree)
        c = af * c + ai * ag;            // ag already relu'd
        const float h = ao * fmaxf(c, 0.f);

        if (lane < 4) {                  // writer: gate==0 && kq==0
            hbuf[p ^ 1][col] = h;
            hob[(size_t)trow * 128] = h; // fire-and-forget, never drained
        }

        LDS_BAR();                       // ONE barrier/step; WAR safe (parity)

        xc = x1; x1 = x2;
        trow += ts;
    }
}

// ---------------------------------------------------------------------------
// Dense + softmax: out[m][c] = softmax_c( h2[m][:] @ Wd[:,c] + bd[c] )
// ---------------------------------------------------------------------------
__global__ __launch_bounds__(256) void dense_softmax(
    const float* __restrict__ h2, const float* __restrict__ Wd,
    const float* __restrict__ bd, float* __restrict__ out)
{
    __shared__ float Wl[128 * 45];
    __shared__ float bl[48];
    __shared__ float hrow[4][128];
    const int tid = threadIdx.x;
    for (int i = tid; i < 128 * 45; i += 256) Wl[i] = Wd[i];
    if (tid < 45) bl[tid] = bd[tid];
    __syncthreads();

    const int w = tid >> 6, l = tid & 63;
    const size_t row0 = (size_t)blockIdx.x * 64;
    for (int rr = 0; rr < 16; ++rr) {
        const size_t m = row0 + (size_t)rr * 4 + w;
        const float2 hv = *(const float2*)&h2[m * 128 + l * 2];
        hrow[w][l * 2] = hv.x;
        hrow[w][l * 2 + 1] = hv.y;
        __syncthreads();
        float lg = -3.0e38f;
        if (l < CC) {
            lg = bl[l];
            #pragma unroll 8
            for (int k = 0; k < 128; ++k) lg = __fmaf_rn(hrow[w][k], Wl[k * 45 + l], lg);
        }
        float mx = lg;
        #pragma unroll
        for (int off = 32; off >= 1; off >>= 1) mx = fmaxf(mx, __shfl_xor(mx, off));
        const float e = (l < CC) ? __expf(lg - mx) : 0.f;
        float sm = e;
        #pragma unroll
        for (int off = 32; off >= 1; off >>= 1) sm += __shfl_xor(sm, off);
        if (l < CC) out[m * 45 + l] = e / sm;
        __syncthreads();
    }
}

// ---------------------------------------------------------------------------
extern "C" void kernel_launch(void* const* d_in, const int* in_sizes, int n_in,
                              void* d_out, int out_size, void* d_ws, size_t ws_size,
                              hipStream_t stream)
{
    const float* x   = (const float*)d_in[0];
    const float* W1f = (const float*)d_in[1];
    const float* U1f = (const float*)d_in[2];
    const float* b1f = (const float*)d_in[3];
    const float* W1b = (const float*)d_in[4];
    const float* U1b = (const float*)d_in[5];
    const float* b1b = (const float*)d_in[6];
    const float* W2f = (const float*)d_in[7];
    const float* U2f = (const float*)d_in[8];
    const float* b2f = (const float*)d_in[9];
    const float* W2b = (const float*)d_in[10];
    const float* U2b = (const float*)d_in[11];
    const float* b2b = (const float*)d_in[12];
    const float* Wd  = (const float*)d_in[13];
    const float* bd  = (const float*)d_in[14];

    // Workspace layout (160 MiB):
    //   xz : 65536 x 512 f32 = 128 MiB   (reused by layer 1 and layer 2)
    //   h  : 65536 x 128 f32 =  32 MiB   (h1, then overwritten by h2)
    float* xz = (float*)d_ws;
    float* h  = (float*)((char*)d_ws + (size_t)65536 * 512 * 4);

    const dim3 gemm_grid(512, 4);      // 65536/128 m-tiles, 512/128 n-tiles
    const dim3 rec_grid(256);          // 128 batch x 2 directions
    const dim3 dense_grid(1024);       // 65536/64 rows

    // Layer 1
    gemm_xz<<<gemm_grid, dim3(256), 0, stream>>>(x, W1f, W1b, b1f, b1b, xz);
    lstm_rec_w16<<<rec_grid, dim3(1024), 0, stream>>>(xz, U1f, U1b, h);
    // Layer 2
    gemm_xz<<<gemm_grid, dim3(256), 0, stream>>>(h, W2f, W2b, b2f, b2b, xz);
    lstm_rec_w16<<<rec_grid, dim3(1024), 0, stream>>>(xz, U2f, U2b, h);
    // Head
    dense_softmax<<<dense_grid, dim3(256), 0, stream>>>(h, Wd, bd, (float*)d_out);
}

// Round 9
// 710.257 us; speedup vs baseline: 1.2472x; 1.2142x over previous
//
#include <hip/hip_runtime.h>

#define TT 512
#define NB 128   // batch
#define DD 128
#define HH 64
#define CC 45

__device__ __forceinline__ float sigf(float x) { return 1.0f / (1.0f + __expf(-x)); }

// LDS-only barrier: syncs LDS visibility WITHOUT draining vmcnt (global
// loads/stores stay in flight across steps). Proven worth 75us/rec (R5->R6).
#define LDS_BAR() asm volatile("s_waitcnt lgkmcnt(0)\n\ts_barrier" ::: "memory")

// Quad-lane xor via DPP quad_perm: VALU-speed (~2cy) vs ds_swizzle (~60cy).
// 0xB1 = perm[1,0,3,2] (lane^1), 0x4E = perm[2,3,0,1] (lane^2).
#define QP_XOR1(x) __int_as_float(__builtin_amdgcn_mov_dpp(__float_as_int(x), 0xB1, 0xF, 0xF, true))
#define QP_XOR2(x) __int_as_float(__builtin_amdgcn_mov_dpp(__float_as_int(x), 0x4E, 0xF, 0xF, true))

// ---------------------------------------------------------------------------
// GEMM: Cout[m][0:512] = A[m][0:128] @ [Wf | Wb] + [biasf | biasb]
// A: [65536][128] row-major. Wf/Wb: [128][256] row-major. Cout: [65536][512].
// BM=128, BN=128, BK=32, 256 threads, 8x8 accumulation per thread. f32 VALU.
// ---------------------------------------------------------------------------
__global__ __launch_bounds__(256) void gemm_xz(
    const float* __restrict__ A, const float* __restrict__ Wf,
    const float* __restrict__ Wb, const float* __restrict__ biasf,
    const float* __restrict__ biasb, float* __restrict__ Cout)
{
    __shared__ float As[32][132];   // [k][m], padded
    __shared__ float Bs[32][132];   // [k][n], padded
    const int tid = threadIdx.x;
    const int m0 = blockIdx.x * 128;
    const int n0 = blockIdx.y * 128;          // global col in [0,512)
    const float* W   = (n0 < 256) ? Wf : Wb;
    const float* bia = (n0 < 256) ? biasf : biasb;
    const int nc0 = n0 & 255;

    const int ty = tid >> 4, tx = tid & 15;
    const int arow = tid >> 3, akv = (tid & 7) << 2;
    const int bkr  = tid >> 5, bnv = (tid & 31) << 2;

    float acc[8][8];
    #pragma unroll
    for (int i = 0; i < 8; ++i)
        #pragma unroll
        for (int j = 0; j < 8; ++j) acc[i][j] = 0.f;

    for (int k0 = 0; k0 < 128; k0 += 32) {
        #pragma unroll
        for (int rr = 0; rr < 4; ++rr) {
            const int r = arow + rr * 32;
            const float4 av = *(const float4*)&A[(size_t)(m0 + r) * 128 + k0 + akv];
            As[akv + 0][r] = av.x; As[akv + 1][r] = av.y;
            As[akv + 2][r] = av.z; As[akv + 3][r] = av.w;
        }
        #pragma unroll
        for (int rr = 0; rr < 4; ++rr) {
            const int kr = bkr + rr * 8;
            *(float4*)&Bs[kr][bnv] =
                *(const float4*)&W[(size_t)(k0 + kr) * 256 + nc0 + bnv];
        }
        __syncthreads();
        #pragma unroll
        for (int k = 0; k < 32; ++k) {
            float av[8], bv[8];
            *(float4*)&av[0] = *(const float4*)&As[k][ty * 8];
            *(float4*)&av[4] = *(const float4*)&As[k][ty * 8 + 4];
            *(float4*)&bv[0] = *(const float4*)&Bs[k][tx * 8];
            *(float4*)&bv[4] = *(const float4*)&Bs[k][tx * 8 + 4];
            #pragma unroll
            for (int i = 0; i < 8; ++i)
                #pragma unroll
                for (int j = 0; j < 8; ++j)
                    acc[i][j] = __fmaf_rn(av[i], bv[j], acc[i][j]);
        }
        __syncthreads();
    }
    #pragma unroll
    for (int i = 0; i < 8; ++i) {
        const size_t rbase = (size_t)(m0 + ty * 8 + i) * 512 + n0 + tx * 8;
        float4 o;
        o.x = acc[i][0] + bia[nc0 + tx * 8 + 0];
        o.y = acc[i][1] + bia[nc0 + tx * 8 + 1];
        o.z = acc[i][2] + bia[nc0 + tx * 8 + 2];
        o.w = acc[i][3] + bia[nc0 + tx * 8 + 3];
        *(float4*)&Cout[rbase] = o;
        o.x = acc[i][4] + bia[nc0 + tx * 8 + 4];
        o.y = acc[i][5] + bia[nc0 + tx * 8 + 5];
        o.z = acc[i][6] + bia[nc0 + tx * 8 + 6];
        o.w = acc[i][7] + bia[nc0 + tx * 8 + 7];
        *(float4*)&Cout[rbase + 4] = o;
    }
}

// ---------------------------------------------------------------------------
// LSTM recurrence, quad-perm design. 256 blocks (batch x dir) x 512 threads.
// Lane bits: [1:0]=gate, [4:2]=colL, [5]=kh (K-half). Wave w owns cols
// w*8..w*8+7. Per lane: 32 pinned U VGPRs (own gate-col x K-half), 32 FMA
// from broadcast LDS h reads. Cross-lane per step:
//   K-half reduce: ONE __shfl_xor(32)            (DS, ~60cy)
//   gate all-gather: 3 quad_perm DPP movs        (VALU, ~2cy each)
// -> no zbuf, no serial finish phase, ONE LDS_BAR/step.
// amdgpu_waves_per_eu(1,2) gives the RA a 256-VGPR/wave budget so the 32
// pinned U values are not spilled (R7 lesson: default heuristic spills >16).
// xz prefetched 2 steps ahead; hout stores fire-and-forget (never drained).
// ---------------------------------------------------------------------------
__global__
__attribute__((amdgpu_flat_work_group_size(512, 512), amdgpu_waves_per_eu(1, 2)))
void lstm_rec_qp(
    const float* __restrict__ xz, const float* __restrict__ Uf,
    const float* __restrict__ Ubw, float* __restrict__ hout)
{
    const int b   = blockIdx.x & 127;
    const int dir = blockIdx.x >> 7;
    const int tid = threadIdx.x;
    const int w    = tid >> 6;          // wave 0..7
    const int lane = tid & 63;
    const int gate = lane & 3;          // 0:i 1:f 2:g 3:o  (quad -> DPP gather)
    const int colL = (lane >> 2) & 7;
    const int kh   = lane >> 5;         // K-half 0/1
    const int col  = w * 8 + colL;      // h column 0..63
    const int gcol = gate * 64 + col;
    const float* U = dir ? Ubw : Uf;

    __shared__ float hbuf[2][64];

    // 32 U values: U[kh*32 + j][gcol], pinned in 4 asm blocks of 8.
    const float* Ug = U + (size_t)(kh * 32) * 256 + gcol;
    float u0  = Ug[ 0*256], u1  = Ug[ 1*256], u2  = Ug[ 2*256], u3  = Ug[ 3*256];
    float u4  = Ug[ 4*256], u5  = Ug[ 5*256], u6  = Ug[ 6*256], u7  = Ug[ 7*256];
    float u8  = Ug[ 8*256], u9  = Ug[ 9*256], u10 = Ug[10*256], u11 = Ug[11*256];
    float u12 = Ug[12*256], u13 = Ug[13*256], u14 = Ug[14*256], u15 = Ug[15*256];
    float u16 = Ug[16*256], u17 = Ug[17*256], u18 = Ug[18*256], u19 = Ug[19*256];
    float u20 = Ug[20*256], u21 = Ug[21*256], u22 = Ug[22*256], u23 = Ug[23*256];
    float u24 = Ug[24*256], u25 = Ug[25*256], u26 = Ug[26*256], u27 = Ug[27*256];
    float u28 = Ug[28*256], u29 = Ug[29*256], u30 = Ug[30*256], u31 = Ug[31*256];
    asm volatile("" : "+v"(u0),"+v"(u1),"+v"(u2),"+v"(u3),
                      "+v"(u4),"+v"(u5),"+v"(u6),"+v"(u7));
    asm volatile("" : "+v"(u8),"+v"(u9),"+v"(u10),"+v"(u11),
                      "+v"(u12),"+v"(u13),"+v"(u14),"+v"(u15));
    asm volatile("" : "+v"(u16),"+v"(u17),"+v"(u18),"+v"(u19),
                      "+v"(u20),"+v"(u21),"+v"(u22),"+v"(u23));
    asm volatile("" : "+v"(u24),"+v"(u25),"+v"(u26),"+v"(u27),
                      "+v"(u28),"+v"(u29),"+v"(u30),"+v"(u31));

    if (tid < 64) hbuf[0][tid] = 0.f;
    float c = 0.f;
    __syncthreads();

    const float* xzb = xz + (size_t)b * TT * 512 + (size_t)dir * 256 + gcol;
    float*       hob = hout + (size_t)b * TT * 128 + (size_t)dir * 64 + col;

    int trow = dir ? (TT - 1) : 0;
    const int ts = dir ? -1 : 1;
    float xc = xzb[(size_t)trow * 512];            // step s
    float x1 = xzb[(size_t)(trow + ts) * 512];     // step s+1

    for (int s = 0; s < TT; ++s) {
        const int p = s & 1;
        float x2 = 0.f;
        if (s + 2 < TT) x2 = xzb[(size_t)(trow + 2 * ts) * 512];  // depth-2

        // 32-FMA K-half partial (broadcast float4 LDS reads: 2 distinct
        // addresses per wave (kh pair) -> 2-way = free per m136)
        float a0 = 0.f, a1 = 0.f, a2 = 0.f, a3 = 0.f;
#define ACC(J, A,B,C,D) { const float4 hv = *(const float4*)&hbuf[p][kh*32 + 4*(J)]; \
        a0 = __fmaf_rn(hv.x, A, a0); a1 = __fmaf_rn(hv.y, B, a1); \
        a2 = __fmaf_rn(hv.z, C, a2); a3 = __fmaf_rn(hv.w, D, a3); }
        ACC(0,u0 ,u1 ,u2 ,u3 ) ACC(1,u4 ,u5 ,u6 ,u7 )
        ACC(2,u8 ,u9 ,u10,u11) ACC(3,u12,u13,u14,u15)
        ACC(4,u16,u17,u18,u19) ACC(5,u20,u21,u22,u23)
        ACC(6,u24,u25,u26,u27) ACC(7,u28,u29,u30,u31)
#undef ACC
        float part = (a0 + a1) + (a2 + a3);

        // K-half reduce: one cross-32 exchange (the only DS op of the step)
        part += __shfl_xor(part, 32);
        const float z = xc + part;

        // own gate's activation (relu for gate 2, sigmoid otherwise)
        const float a = (gate == 2) ? fmaxf(z, 0.f) : sigf(z);

        // gate all-gather within the quad: 3 DPP movs (VALU-speed)
        const float b0 = QP_XOR1(a);        // act of gate^1
        const float b1 = QP_XOR2(a);        // act of gate^2
        const float b2 = QP_XOR2(b0);       // act of gate^3
        const float ai = (gate == 0) ? a : (gate == 1) ? b0 : (gate == 2) ? b1 : b2;
        const float af = (gate == 1) ? a : (gate == 0) ? b0 : (gate == 3) ? b1 : b2;
        const float ag = (gate == 2) ? a : (gate == 3) ? b0 : (gate == 0) ? b1 : b2;
        const float ao = (gate == 3) ? a : (gate == 2) ? b0 : (gate == 1) ? b1 : b2;

        // replicated state update (all 8 lanes of a column agree)
        c = af * c + ai * ag;               // ag already relu'd
        const float h = ao * fmaxf(c, 0.f);

        if ((lane & 0x23) == 0) {           // writer: gate==0 && kh==0
            hbuf[p ^ 1][col] = h;
            hob[(size_t)trow * 128] = h;    // fire-and-forget, never drained
        }

        LDS_BAR();                          // ONE barrier/step; WAR safe (parity)

        xc = x1; x1 = x2;
        trow += ts;
    }
}

// ---------------------------------------------------------------------------
// Dense + softmax: out[m][c] = softmax_c( h2[m][:] @ Wd[:,c] + bd[c] )
// ---------------------------------------------------------------------------
__global__ __launch_bounds__(256) void dense_softmax(
    const float* __restrict__ h2, const float* __restrict__ Wd,
    const float* __restrict__ bd, float* __restrict__ out)
{
    __shared__ float Wl[128 * 45];
    __shared__ float bl[48];
    __shared__ float hrow[4][128];
    const int tid = threadIdx.x;
    for (int i = tid; i < 128 * 45; i += 256) Wl[i] = Wd[i];
    if (tid < 45) bl[tid] = bd[tid];
    __syncthreads();

    const int w = tid >> 6, l = tid & 63;
    const size_t row0 = (size_t)blockIdx.x * 64;
    for (int rr = 0; rr < 16; ++rr) {
        const size_t m = row0 + (size_t)rr * 4 + w;
        const float2 hv = *(const float2*)&h2[m * 128 + l * 2];
        hrow[w][l * 2] = hv.x;
        hrow[w][l * 2 + 1] = hv.y;
        __syncthreads();
        float lg = -3.0e38f;
        if (l < CC) {
            lg = bl[l];
            #pragma unroll 8
            for (int k = 0; k < 128; ++k) lg = __fmaf_rn(hrow[w][k], Wl[k * 45 + l], lg);
        }
        float mx = lg;
        #pragma unroll
        for (int off = 32; off >= 1; off >>= 1) mx = fmaxf(mx, __shfl_xor(mx, off));
        const float e = (l < CC) ? __expf(lg - mx) : 0.f;
        float sm = e;
        #pragma unroll
        for (int off = 32; off >= 1; off >>= 1) sm += __shfl_xor(sm, off);
        if (l < CC) out[m * 45 + l] = e / sm;
        __syncthreads();
    }
}

// ---------------------------------------------------------------------------
extern "C" void kernel_launch(void* const* d_in, const int* in_sizes, int n_in,
                              void* d_out, int out_size, void* d_ws, size_t ws_size,
                              hipStream_t stream)
{
    const float* x   = (const float*)d_in[0];
    const float* W1f = (const float*)d_in[1];
    const float* U1f = (const float*)d_in[2];
    const float* b1f = (const float*)d_in[3];
    const float* W1b = (const float*)d_in[4];
    const float* U1b = (const float*)d_in[5];
    const float* b1b = (const float*)d_in[6];
    const float* W2f = (const float*)d_in[7];
    const float* U2f = (const float*)d_in[8];
    const float* b2f = (const float*)d_in[9];
    const float* W2b = (const float*)d_in[10];
    const float* U2b = (const float*)d_in[11];
    const float* b2b = (const float*)d_in[12];
    const float* Wd  = (const float*)d_in[13];
    const float* bd  = (const float*)d_in[14];

    // Workspace layout (160 MiB):
    //   xz : 65536 x 512 f32 = 128 MiB   (reused by layer 1 and layer 2)
    //   h  : 65536 x 128 f32 =  32 MiB   (h1, then overwritten by h2)
    float* xz = (float*)d_ws;
    float* h  = (float*)((char*)d_ws + (size_t)65536 * 512 * 4);

    const dim3 gemm_grid(512, 4);      // 65536/128 m-tiles, 512/128 n-tiles
    const dim3 rec_grid(256);          // 128 batch x 2 directions
    const dim3 dense_grid(1024);       // 65536/64 rows

    // Layer 1
    gemm_xz<<<gemm_grid, dim3(256), 0, stream>>>(x, W1f, W1b, b1f, b1b, xz);
    lstm_rec_qp<<<rec_grid, dim3(512), 0, stream>>>(xz, U1f, U1b, h);
    // Layer 2
    gemm_xz<<<gemm_grid, dim3(256), 0, stream>>>(h, W2f, W2b, b2f, b2b, xz);
    lstm_rec_qp<<<rec_grid, dim3(512), 0, stream>>>(xz, U2f, U2b, h);
    // Head
    dense_softmax<<<dense_grid, dim3(256), 0, stream>>>(h, Wd, bd, (float*)d_out);
}